// Round 1
// 336.291 us; speedup vs baseline: 1.0754x; 1.0754x over previous
//
#include <hip/hip_runtime.h>

// Problem constants
#define N_BATCH 8
#define CI 8
#define CO 16
#define ODIM 66
#define OSP (66*66*66)        // 287496 per (n, co) slab
#define GROUPS 4

typedef _Float16 half8 __attribute__((ext_vector_type(8)));
typedef float f32x4 __attribute__((ext_vector_type(4)));

// MFMA conv tiling: block = (n, od-chunk of 6, 8 oh-rows). 8*66 = 528 positions
// = 33 tiles of 16 -> 3 waves x 11 tiles. K = 28 taps x 8 ci = 7 chunks of 32.
// Sliding window over od: LDS ring of 4 z-planes; per od step we stage ONE new
// plane (issue loads before MFMA, ds_write after -> T14 latency hiding) instead
// of re-staging 3 planes per od like the previous version.
#define OHT 8
#define NWAVES 3
#define TPW 11
#define NTHR 192
#define XIH 10                 // staged ih rows (8 + 2 halo)
#define XIW 68                 // staged iw (64 + 2+2 zero halo)
#define PLPOS (XIH*XIW)        // 680 positions per z-plane
#define PLH (PLPOS*8)          // 5440 halfs per z-plane (10.88 KB)
#define RING 4                 // 3 active planes + 1 being staged
#define LOD 6                  // od planes per block (11 chunks * 6 = 66)
#define NODC 11
#define WSZ (28*16*8)          // 3584 halfs, tap 27 = zero pad
#define XPLANE 262144          // 64*64*64 floats per (n,ci) plane

// ws layout (floats): [0..31] sum, [32..63] sumsq
__global__ __launch_bounds__(64) void zero_stats(float* ws) {
    ws[threadIdx.x] = 0.0f;
}

// Issue the 28 (4 pos x 8 ci) global loads for one z-plane into registers.
// Lanes consecutive -> iw consecutive -> each of the 8 ci loads is coalesced.
__device__ __forceinline__ void stage_issue(
    const float* __restrict__ x, size_t nbase, int id, int oh0, int tid,
    float xr[4][8], int sp[4], bool sok[4])
{
    #pragma unroll
    for (int it = 0; it < 4; ++it) {
        int p   = tid + it * NTHR;            // < 768, valid if p < 680
        int ihl = p / XIW;
        int iw  = p - ihl * XIW - 2;
        int ih  = oh0 - 2 + ihl;
        bool ok = (p < PLPOS) & ((unsigned)id < 64u) &
                  ((unsigned)ih < 64u) & ((unsigned)iw < 64u);
        size_t base = nbase + (ok ? ((size_t)id * 4096 + (size_t)(ih * 64 + iw)) : 0);
        #pragma unroll
        for (int ci = 0; ci < 8; ++ci)
            xr[it][ci] = x[base + (size_t)ci * XPLANE];   // clamped addr, always safe
        sp[it] = p; sok[it] = ok;
    }
}

// Convert + publish one staged plane into ring slot (contiguous b128 writes,
// conflict-free). Caller places this AFTER the MFMA block (vmcnt hides latency).
__device__ __forceinline__ void stage_write(
    _Float16* XT, int slot, const float xr[4][8], const int sp[4], const bool sok[4])
{
    #pragma unroll
    for (int it = 0; it < 4; ++it) {
        if (sp[it] < PLPOS) {
            half8 h;
            #pragma unroll
            for (int ci = 0; ci < 8; ++ci)
                h[ci] = sok[it] ? (_Float16)xr[it][ci] : (_Float16)0.0f;
            *(half8*)&XT[slot * PLH + sp[it] * 8] = h;
        }
    }
}

__global__ __launch_bounds__(NTHR, 2) void conv_mfma(
    const float* __restrict__ x, const float* __restrict__ w,
    float* __restrict__ out, float* __restrict__ stats)
{
    __shared__ _Float16 XT[RING * PLH];   // 43,520 B ring of z-planes [slot][ih][iw][ci]
    __shared__ _Float16 WT[WSZ];          // 7,168 B  [t][co][ci], tap 27 = zeros
    __shared__ float reds[2][NWAVES][GROUPS];

    const int tid = threadIdx.x;
    const int n   = blockIdx.z;
    const int od0 = blockIdx.y * LOD;
    const int oh0 = blockIdx.x * OHT;

    // Stage weights (fp16 round-trip per reference). Thread owns one (t,co).
    for (int i = tid; i < 28 * 16; i += NTHR) {
        int t = i >> 4, co = i & 15;
        half8 h;
        #pragma unroll
        for (int ci = 0; ci < 8; ++ci) {
            float v = (t < 27) ? w[(ci * 16 + co) * 27 + t] : 0.0f;
            h[ci] = (_Float16)v;
        }
        *(half8*)&WT[i * 8] = h;
    }

    const size_t nbase = (size_t)(n * CI) * XPLANE;

    // Prologue: planes j=0..2 (ids od0-2..od0) into ring slots 0..2.
    {
        float xr[4][8]; int sp[4]; bool sok[4];
        #pragma unroll
        for (int j = 0; j < 3; ++j) {
            stage_issue(x, nbase, od0 - 2 + j, oh0, tid, xr, sp, sok);
            stage_write(XT, j, xr, sp, sok);
        }
    }
    __syncthreads();

    const int lane = tid & 63;
    const int wv   = tid >> 6;
    const int q    = lane >> 4;     // tap-within-chunk (A/B k), row-block (D)
    const int col  = lane & 15;     // co (B/D), position m (A)

    // B fragments + per-chunk tap decomposition. t = c*4+q; t=27 clamps to 26
    // for addressing (its bfrag is zero so the A value is irrelevant).
    half8 bfrag[7];
    int sub[7], kd2[7];
    #pragma unroll
    for (int c = 0; c < 7; ++c) {
        int t = c * 4 + q;
        bfrag[c] = *(const half8*)&WT[(t * 16 + col) * 8];
        if (t > 26) t = 26;
        int kd = t / 9, r = t - kd * 9, kh = r / 3, kw = r - kh * 3;
        sub[c] = (kh * XIW + kw) * 8;   // within-plane tap offset (halfs)
        kd2[c] = 2 - kd;                // ring rotation term: slot = (k + kd2) & 3
    }

    // Within-plane base address per tile: p = (wv*11+i)*16 + col in 8x66 grid.
    int basein[TPW];
    #pragma unroll
    for (int i = 0; i < TPW; ++i) {
        int p   = (wv * TPW + i) * 16 + col;
        int ohl = p / 66, ow = p - ohl * 66;
        basein[i] = ((ohl + 2) * XIW + (ow + 2)) * 8;
    }

    float s = 0.0f, ss = 0.0f;               // stats accumulated across all LOD ods
    const int co = col;
    float* slab0 = out + (size_t)(n * CO + co) * OSP + (size_t)od0 * 4356 + oh0 * 66;

    float xr[4][8]; int sp[4]; bool sok[4];  // in-flight staging registers (T14)

    for (int k = 0; k < LOD; ++k) {
        const bool stg = (k < LOD - 1);
        // Issue next plane's loads BEFORE compute: id = od0+k+1 -> slot (k+3)&3.
        // That slot is not read by compute of od0+k (it reads k,k+1,k+2 mod 4),
        // so no barrier is needed between issue/write and this od's MFMAs.
        if (stg) stage_issue(x, nbase, od0 + k + 1, oh0, tid, xr, sp, sok);

        f32x4 acc[TPW];
        #pragma unroll
        for (int i = 0; i < TPW; ++i) acc[i] = (f32x4){0.f, 0.f, 0.f, 0.f};

        int aoffc[7];   // ring slot base + tap offset for this od
        #pragma unroll
        for (int c = 0; c < 7; ++c)
            aoffc[c] = ((k + kd2[c]) & 3) * PLH - sub[c];

        // 77 (ds_read_b128 + MFMA); c outer keeps 11 inner MFMAs independent.
        #pragma unroll
        for (int c = 0; c < 7; ++c) {
            #pragma unroll
            for (int i = 0; i < TPW; ++i) {
                half8 a = *(const half8*)&XT[basein[i] + aoffc[c]];
                acc[i] = __builtin_amdgcn_mfma_f32_16x16x32_f16(a, bfrag[c], acc[i], 0, 0, 0);
            }
        }

        // Epilogue for od = od0+k: ReLU + store + stats accumulate.
        float* slab = slab0 + (size_t)k * 4356;
        #pragma unroll
        for (int i = 0; i < TPW; ++i) {
            #pragma unroll
            for (int r = 0; r < 4; ++r) {
                int p   = (wv * TPW + i) * 16 + q * 4 + r;
                int ohl = p / 66, ow = p - ohl * 66;
                if (oh0 + ohl < ODIM) {
                    float v = fmaxf(acc[i][r], 0.0f);
                    slab[ohl * 66 + ow] = v;
                    s += v;
                    ss = fmaf(v, v, ss);
                }
            }
        }

        // Publish staged plane (vmcnt wait lands here, hidden under the MFMAs),
        // then one barrier per od makes it visible before od0+k+1's compute.
        if (stg) stage_write(XT, (k + 3) & 3, xr, sp, sok);
        __syncthreads();
    }

    // Reduce: xor16/32 merges lanes with same co; xor1/2 merges the 4 co of a group.
    s += __shfl_xor(s, 16, 64);  ss += __shfl_xor(ss, 16, 64);
    s += __shfl_xor(s, 32, 64);  ss += __shfl_xor(ss, 32, 64);
    s += __shfl_xor(s, 1, 64);   ss += __shfl_xor(ss, 1, 64);
    s += __shfl_xor(s, 2, 64);   ss += __shfl_xor(ss, 2, 64);
    if (lane < 16 && (lane & 3) == 0) {
        reds[0][wv][lane >> 2] = s;
        reds[1][wv][lane >> 2] = ss;
    }
    __syncthreads();
    if (tid < GROUPS) {
        float ts = 0.0f, tss = 0.0f;
        #pragma unroll
        for (int v = 0; v < NWAVES; ++v) { ts += reds[0][v][tid]; tss += reds[1][v][tid]; }
        atomicAdd(&stats[n * GROUPS + tid], ts);
        atomicAdd(&stats[32 + n * GROUPS + tid], tss);
    }
}

// In-place normalize: out = (y - mean) * rstd * gamma + beta.
// finalize folded in: each block derives mean/rstd from the raw sums (cheap).
#define NORM_ITER 8
#define NORM_NTHR 256
__global__ __launch_bounds__(NORM_NTHR) void norm_kernel(
    float* __restrict__ out, const float* __restrict__ ws,
    const float* __restrict__ gamma, const float* __restrict__ beta)
{
    const int slab = blockIdx.y;           // n*16 + co
    const int n  = slab >> 4;
    const int co = slab & 15;
    const int gi = n * GROUPS + (co >> 2);
    const float cnt  = 4.0f * (float)OSP;
    const float mean = ws[gi] / cnt;
    const float var  = ws[32 + gi] / cnt - mean * mean;
    const float rstd = rsqrtf(var + 1e-5f);
    const float scale = rstd * gamma[co];
    const float shift = beta[co] - mean * scale;

    float4* p = (float4*)(out + (size_t)slab * OSP);
    const int base = blockIdx.x * (NORM_NTHR * NORM_ITER) + threadIdx.x;
    #pragma unroll
    for (int it = 0; it < NORM_ITER; ++it) {
        const int idx = base + it * NORM_NTHR;
        if (idx < OSP / 4) {
            float4 v = p[idx];
            v.x = fmaf(v.x, scale, shift);
            v.y = fmaf(v.y, scale, shift);
            v.z = fmaf(v.z, scale, shift);
            v.w = fmaf(v.w, scale, shift);
            p[idx] = v;
        }
    }
}

extern "C" void kernel_launch(void* const* d_in, const int* in_sizes, int n_in,
                              void* d_out, int out_size, void* d_ws, size_t ws_size,
                              hipStream_t stream) {
    const float* x     = (const float*)d_in[0];
    const float* w     = (const float*)d_in[1];
    const float* gamma = (const float*)d_in[2];
    const float* beta  = (const float*)d_in[3];
    float* out = (float*)d_out;
    float* ws  = (float*)d_ws;

    zero_stats<<<1, 64, 0, stream>>>(ws);

    dim3 grid1((ODIM + OHT - 1) / OHT, NODC, N_BATCH);     // (9, 11, 8) = 792 blocks
    conv_mfma<<<grid1, NTHR, 0, stream>>>(x, w, out, ws);

    const int f4_per_slab = OSP / 4;                       // 71874
    dim3 grid2((f4_per_slab + NORM_NTHR * NORM_ITER - 1) / (NORM_NTHR * NORM_ITER),
               N_BATCH * CO);                              // (36, 128)
    norm_kernel<<<grid2, NORM_NTHR, 0, stream>>>(out, ws, gamma, beta);
}